// Round 1
// baseline (299.932 us; speedup 1.0000x reference)
//
#include <hip/hip_runtime.h>

#define B_ 32
#define N_ 8732
#define N2_ 17464
#define C_ 21
#define K_ 200
#define TPB 256
#define NCLS 20
#define CONF_T 0.01f
#define NMS_T 0.45f

typedef unsigned long long u64;
typedef unsigned int u32;

// ---------------------------------------------------------------------------
// Kernel 1: softmax over C=21 for both views, written transposed to [B, C, 2N]
// ---------------------------------------------------------------------------
__global__ __launch_bounds__(TPB) void softmax_kernel(
    const float* __restrict__ conf1, const float* __restrict__ conf2,
    float* __restrict__ scores)
{
  int n = blockIdx.x * TPB + threadIdx.x;
  int b = blockIdx.y;
  if (n >= N2_) return;
  const float* src = (n < N_) ? (conf1 + ((size_t)b * N_ + n) * C_)
                              : (conf2 + ((size_t)b * N_ + (n - N_)) * C_);
  float x[C_];
#pragma unroll
  for (int i = 0; i < C_; ++i) x[i] = src[i];
  float m = x[0];
#pragma unroll
  for (int i = 1; i < C_; ++i) m = fmaxf(m, x[i]);
  float e[C_];
  float sum = 0.0f;
#pragma unroll
  for (int i = 0; i < C_; ++i) { e[i] = expf(x[i] - m); sum += e[i]; }
  float* dst = scores + (size_t)b * C_ * N2_ + n;
#pragma unroll
  for (int i = 0; i < C_; ++i) dst[(size_t)i * N2_] = e[i] / sum;  // coalesced per class
}

// ---------------------------------------------------------------------------
// Kernel 2: per-(image,class) exact top-200 (radix select + bitonic sort),
// decode selected boxes, greedy NMS via IoU bitmask rows, compact output.
// One 256-thread block per (b, c), c in [1, 21).
// ---------------------------------------------------------------------------
__global__ __launch_bounds__(TPB) void nms_kernel(
    const float* __restrict__ scores,
    const float4* __restrict__ loc1,
    const float4* __restrict__ loc2,
    const float4* __restrict__ dbox,
    float* __restrict__ out)
{
  const int t = threadIdx.x;
  const int bimg = blockIdx.x / NCLS;
  const int cls = 1 + (blockIdx.x % NCLS);
  const float* sc = scores + ((size_t)bimg * C_ + cls) * N2_;

  __shared__ u32 hist[TPB];
  __shared__ u32 sh_selbin, sh_above, sh_cnt;
  __shared__ u32 sh_ngt, sh_neq, sh_run;
  __shared__ u32 wcnt[4];
  __shared__ u64 pool[TPB];
  __shared__ float bx1[K_], by1[K_], bx2[K_], by2[K_], bar[K_], bsc[K_];
  __shared__ u64 rowmask[K_][4];
  __shared__ u64 validmask[4];
  __shared__ u64 keepmask[4];

  // ---- radix select: key (uint bits) of the 200th-largest score > CONF_T ----
  // positive fp32: uint bit pattern is order-isomorphic to value.
  u32 prefix = 0, need = K_, above = 0, selcnt = 0;
  bool undershoot = false;  // fewer than 200 scores above threshold
  for (int pass = 0; pass < 4 && !undershoot; ++pass) {
    const int shift = 24 - pass * 8;
    hist[t] = 0;
    __syncthreads();
    for (int i = t; i < N2_; i += TPB) {
      float s = sc[i];
      u32 k = (s > CONF_T) ? __float_as_uint(s) : 0u;
      if (k != 0u) {
        u32 hi = (pass == 0) ? 0u : (k >> (shift + 8));
        u32 pf = (pass == 0) ? 0u : prefix;
        if (hi == pf) atomicAdd(&hist[(k >> shift) & 255u], 1u);
      }
    }
    __syncthreads();
    // Hillis-Steele suffix sums: hist[t] -> S[t] = sum_{t'>=t} count[t']
    u32 v = hist[t];
    for (int off = 1; off < TPB; off <<= 1) {
      u32 add = (t + off < TPB) ? hist[t + off] : 0u;
      __syncthreads();
      v += add;
      hist[t] = v;
      __syncthreads();
    }
    u32 S0 = hist[0];
    if (pass == 0 && S0 < need) {
      above = S0;       // G = total valid count V
      undershoot = true;
    } else {
      u32 S_t = v;
      u32 S_n = (t < TPB - 1) ? hist[t + 1] : 0u;
      if (S_t >= need && S_n < need) {  // exactly one thread
        sh_selbin = (u32)t; sh_above = S_n; sh_cnt = S_t - S_n;
      }
      __syncthreads();
      prefix = (prefix << 8) | sh_selbin;
      above += sh_above;
      need -= sh_above;
      selcnt = sh_cnt;
      __syncthreads();
    }
  }
  const u32 Tkey = undershoot ? 0u : prefix;   // key of 200th largest (0 if <200 valid)
  const u32 G = above;                          // count of keys strictly > Tkey
  const u32 need_eq = undershoot ? 0u : need;   // boundary ties to take (smallest idx)
  const bool fallback = (!undershoot) && (G + selcnt > (u32)TPB);

  // ---- collect candidate pool (order fixed later by sort) ----
  pool[t] = 0ULL;
  if (t == 0) { sh_ngt = 0; sh_neq = 0; sh_run = 0; }
  __syncthreads();
  for (int i = t; i < N2_; i += TPB) {
    float s = sc[i];
    u32 k = (s > CONF_T) ? __float_as_uint(s) : 0u;
    if (k > Tkey) {
      u32 slot = atomicAdd(&sh_ngt, 1u);
      if (slot < (u32)TPB)
        pool[slot] = ((u64)k << 32) | (u64)(0xFFFFFFFFu - (u32)i);
    } else if (!fallback && Tkey != 0u && k == Tkey) {
      u32 e = atomicAdd(&sh_neq, 1u);
      if (G + e < (u32)TPB)
        pool[G + e] = ((u64)Tkey << 32) | (u64)(0xFFFFFFFFu - (u32)i);
    }
  }
  __syncthreads();
  if (fallback) {
    // rare: >56 exact ties at the boundary value — ordered scan, smallest indices
    for (int base = 0; base < N2_; base += TPB) {
      int i = base + t;
      bool eq = false;
      if (i < N2_) {
        float s = sc[i];
        u32 k = (s > CONF_T) ? __float_as_uint(s) : 0u;
        eq = (k == Tkey);
      }
      u64 bal = __ballot(eq);
      int lane = t & 63, wv = t >> 6;
      if (lane == 0) wcnt[wv] = (u32)__popcll(bal);
      __syncthreads();
      u32 base_run = sh_run;
      u32 wbase = base_run;
      for (int w2 = 0; w2 < wv; ++w2) wbase += wcnt[w2];
      u32 mypos = wbase + (u32)__popcll(bal & ((1ULL << lane) - 1ULL));
      if (eq && mypos < need_eq)
        pool[G + mypos] = ((u64)Tkey << 32) | (u64)(0xFFFFFFFFu - (u32)i);
      __syncthreads();
      if (t == 0) sh_run = base_run + wcnt[0] + wcnt[1] + wcnt[2] + wcnt[3];
      __syncthreads();
    }
  }
  __syncthreads();

  // ---- bitonic sort pool[256] descending by (score_bits, ~idx) ----
  // equal scores -> larger ~idx first -> smaller idx first (stable like lax.top_k)
  for (int kk = 2; kk <= TPB; kk <<= 1) {
    for (int j = kk >> 1; j > 0; j >>= 1) {
      int p = t ^ j;
      if (p > t) {
        u64 a = pool[t], c2 = pool[p];
        bool desc = ((t & kk) == 0);
        if (desc ? (a < c2) : (a > c2)) { pool[t] = c2; pool[p] = a; }
      }
      __syncthreads();
    }
  }

  // ---- decode boxes for top-200 candidates ----
  float x1 = 0.f, y1 = 0.f, x2 = 0.f, y2 = 0.f, area = 0.f, scv = 0.f;
  if (t < K_) {
    u64 e = pool[t];
    u32 kb = (u32)(e >> 32);
    if (kb != 0u) {
      scv = __uint_as_float(kb);
      u32 idx = 0xFFFFFFFFu - (u32)(e & 0xFFFFFFFFu);
      int nn = (idx < (u32)N_) ? (int)idx : (int)(idx - N_);
      float4 l = (idx < (u32)N_) ? loc1[(size_t)bimg * N_ + nn]
                                 : loc2[(size_t)bimg * N_ + nn];
      float4 d = dbox[nn];
      float cx = d.x + l.x * 0.1f * d.z;
      float cy = d.y + l.y * 0.1f * d.w;
      float w = d.z * expf(l.z * 0.2f);
      float h = d.w * expf(l.w * 0.2f);
      x1 = cx - w * 0.5f; y1 = cy - h * 0.5f;
      x2 = cx + w * 0.5f; y2 = cy + h * 0.5f;
      if (idx >= (u32)N_) {  // horizontal flip of second view
        float tmp = 1.0f - x2; x2 = 1.0f - x1; x1 = tmp;
      }
      area = (x2 - x1) * (y2 - y1);
    }
    bx1[t] = x1; by1[t] = y1; bx2[t] = x2; by2[t] = y2; bar[t] = area; bsc[t] = scv;
  }
  {
    bool myvalid = (t < K_) && (scv > CONF_T);
    u64 bal = __ballot(myvalid);
    if ((t & 63) == 0) validmask[t >> 6] = bal;
  }
  __syncthreads();

  // ---- build IoU>thresh bitmask rows: thread j owns row j ----
  if (t < K_) {
    u64 r0 = 0, r1 = 0, r2 = 0, r3 = 0;
    for (int k2 = 0; k2 < K_; ++k2) {
      float ox1 = fmaxf(x1, bx1[k2]);
      float oy1 = fmaxf(y1, by1[k2]);
      float ox2 = fminf(x2, bx2[k2]);
      float oy2 = fminf(y2, by2[k2]);
      float iw = fmaxf(ox2 - ox1, 0.0f);
      float ih = fmaxf(oy2 - oy1, 0.0f);
      float inter = iw * ih;
      float uni = area + bar[k2] - inter;
      u64 bit = (inter > NMS_T * uni) ? 1ULL : 0ULL;
      u64 sh2 = bit << (k2 & 63);
      int w2 = k2 >> 6;
      if (w2 == 0) r0 |= sh2; else if (w2 == 1) r1 |= sh2;
      else if (w2 == 2) r2 |= sh2; else r3 |= sh2;
    }
    rowmask[t][0] = r0; rowmask[t][1] = r1; rowmask[t][2] = r2; rowmask[t][3] = r3;
  }
  __syncthreads();

  // ---- sequential greedy NMS scan: wave 0 only, replicated register state ----
  if (t < 64) {
    u64 v0 = validmask[0], v1 = validmask[1], v2 = validmask[2], v3 = validmask[3];
    u64 s0 = 0, s1 = 0, s2 = 0, s3 = 0;
    u64 k0 = 0, k1 = 0, k2m = 0, k3 = 0;
#pragma unroll 4
    for (int j = 0; j < K_; ++j) {
      u64 r0 = rowmask[j][0], r1 = rowmask[j][1], r2 = rowmask[j][2], r3 = rowmask[j][3];
      int q = j >> 6;
      u64 bit = 1ULL << (j & 63);
      u64 vw = (q == 0) ? v0 : (q == 1) ? v1 : (q == 2) ? v2 : v3;
      u64 sw = (q == 0) ? s0 : (q == 1) ? s1 : (q == 2) ? s2 : s3;
      if ((vw & bit) && !(sw & bit)) {
        s0 |= r0; s1 |= r1; s2 |= r2; s3 |= r3;
        if (q == 0) k0 |= bit; else if (q == 1) k1 |= bit;
        else if (q == 2) k2m |= bit; else k3 |= bit;
      }
    }
    if (t == 0) { keepmask[0] = k0; keepmask[1] = k1; keepmask[2] = k2m; keepmask[3] = k3; }
  }
  __syncthreads();

  // ---- compact kept entries to out[b][c][pos] = (score, x1, y1, x2, y2) ----
  if (t < K_) {
    int q = t >> 6, bitp = t & 63;
    u64 kw = keepmask[q];
    if ((kw >> bitp) & 1ULL) {
      int pos = (int)__popcll(kw & ((1ULL << bitp) - 1ULL));
      for (int w2 = 0; w2 < q; ++w2) pos += (int)__popcll(keepmask[w2]);
      float* o = out + ((((size_t)bimg * C_) + cls) * K_ + (size_t)pos) * 5;
      o[0] = scv; o[1] = x1; o[2] = y1; o[3] = x2; o[4] = y2;
    }
  }
}

extern "C" void kernel_launch(void* const* d_in, const int* in_sizes, int n_in,
                              void* d_out, int out_size, void* d_ws, size_t ws_size,
                              hipStream_t stream) {
  const float* loc1 = (const float*)d_in[0];
  const float* conf1 = (const float*)d_in[1];
  const float* loc2 = (const float*)d_in[2];
  const float* conf2 = (const float*)d_in[3];
  const float* dbox = (const float*)d_in[4];
  float* out = (float*)d_out;
  float* scores = (float*)d_ws;  // [B, C, 2N] fp32 = 44.7 MB

  // output is re-poisoned before every timed launch; zero it (class 0 + dropped slots)
  hipMemsetAsync(d_out, 0, (size_t)out_size * sizeof(float), stream);

  dim3 g1((N2_ + TPB - 1) / TPB, B_);
  softmax_kernel<<<g1, TPB, 0, stream>>>(conf1, conf2, scores);

  nms_kernel<<<B_ * NCLS, TPB, 0, stream>>>(
      scores, (const float4*)loc1, (const float4*)loc2, (const float4*)dbox, out);
}

// Round 2
// 199.316 us; speedup vs baseline: 1.5048x; 1.5048x over previous
//
#include <hip/hip_runtime.h>

#define B_ 32
#define N_ 8732
#define N2_ 17464
#define N4_ 4366      // N2_/4 exactly
#define C_ 21
#define NCLS 20
#define K_ 200
#define CONF_T 0.01f
#define NMS_T 0.45f
#define TPB_S 256
#define TPB_N 512
#define POOL 1024
#define HBINS 2048

typedef unsigned long long u64;
typedef unsigned int u32;

// ---------------------------------------------------------------------------
// Kernel 1: softmax over C=21, LDS-staged coalesced float4 loads, transposed
// write to [B, NCLS, 2N] (class 0 skipped — never read downstream).
// Grid: (ceil(N/256), B, 2 views).
// ---------------------------------------------------------------------------
__global__ __launch_bounds__(TPB_S) void softmax_kernel(
    const float* __restrict__ conf1, const float* __restrict__ conf2,
    float* __restrict__ scores)
{
  __shared__ float lds[TPB_S * C_];   // 21 KB
  const int t = threadIdx.x;
  const int tile = blockIdx.x * TPB_S;
  const int b = blockIdx.y;
  const int view = blockIdx.z;
  int cnt = N_ - tile; if (cnt > TPB_S) cnt = TPB_S;   // 256 or 28: cnt*21 % 4 == 0
  const float* conf = view ? conf2 : conf1;
  const float4* src = (const float4*)(conf + ((size_t)b * N_ + tile) * C_);  // 16B-aligned
  float4* l4 = (float4*)lds;
  const int n4 = (cnt * C_) >> 2;
  for (int i = t; i < n4; i += TPB_S) l4[i] = src[i];
  __syncthreads();
  if (t < cnt) {
    const float* row = lds + t * C_;  // stride 21 across lanes: 2-way max = free
    float m = row[0];
#pragma unroll
    for (int i = 1; i < C_; ++i) m = fmaxf(m, row[i]);
    float e[C_];
    float sum = 0.0f;
#pragma unroll
    for (int i = 0; i < C_; ++i) { e[i] = expf(row[i] - m); sum += e[i]; }
    float* dst = scores + ((size_t)b * NCLS) * N2_ + (size_t)view * N_ + tile + t;
#pragma unroll
    for (int c = 1; c < C_; ++c) dst[(size_t)(c - 1) * N2_] = e[c] / sum;  // coalesced
  }
}

// ---------------------------------------------------------------------------
// Kernel 2: per-(image,class): coarse radix cutoff (1 global hist pass,
// usually) -> collect <=1024 candidates to LDS -> bitonic sort by composite
// (score_bits<<32)|~idx (== exact top_k semantics incl. ties) -> decode ->
// IoU bitmask NMS -> compact. One 512-thread block per (b, c).
// ---------------------------------------------------------------------------
__global__ __launch_bounds__(TPB_N) void nms_kernel(
    const float* __restrict__ scores,
    const float4* __restrict__ loc1,
    const float4* __restrict__ loc2,
    const float4* __restrict__ dbox,
    float* __restrict__ out)
{
  const int t = threadIdx.x;
  const int bimg = blockIdx.x / NCLS;
  const int cls = 1 + (blockIdx.x % NCLS);
  const float4* sc4 = (const float4*)(scores + ((size_t)bimg * NCLS + (cls - 1)) * N2_);

  __shared__ u32 hist[HBINS];            // 8 KB
  __shared__ u64 pool[POOL];             // 8 KB
  __shared__ u32 sh_sel, sh_Sb, sh_Sn, sh_nc;
  __shared__ float bx1[K_], by1[K_], bx2[K_], by2[K_], bar[K_];
  __shared__ u64 rowmask[K_][4];         // 6.4 KB
  __shared__ u64 validmask[4];
  __shared__ u64 keepmask[4];

  // ---- multi-level coarse select: find loKey with need <= count(key>=loKey) <= POOL ----
  u32 prefix = 0, Gacc = 0, loKey = 0;
  bool done = false;
  for (int lvl = 0; lvl < 3 && !done; ++lvl) {
    const int shift = (lvl == 0) ? 20 : (lvl == 1) ? 10 : 0;
    const u32 bmask = (lvl == 0) ? 2047u : 1023u;
    const int mshift = (lvl == 1) ? 20 : 10;   // prefix-match shift (unused at lvl 0)
    for (int h = t; h < HBINS; h += TPB_N) hist[h] = 0u;
    __syncthreads();
    for (int i = t; i < N4_; i += TPB_N) {
      float4 s4 = sc4[i];
      float ss[4] = {s4.x, s4.y, s4.z, s4.w};
#pragma unroll
      for (int c2 = 0; c2 < 4; ++c2) {
        if (ss[c2] > CONF_T) {
          u32 k = __float_as_uint(ss[c2]);   // positive fp32: bits order-isomorphic
          if (lvl == 0 || (k >> mshift) == prefix)
            atomicAdd(&hist[(k >> shift) & bmask], 1u);
        }
      }
    }
    __syncthreads();
    // Hillis-Steele suffix sums over 2048 bins (each thread owns 4 bins)
    for (int off = 1; off < HBINS; off <<= 1) {
      u32 a0 = (t + off < HBINS) ? hist[t + off] : 0u;
      u32 a1 = (t + 512 + off < HBINS) ? hist[t + 512 + off] : 0u;
      u32 a2 = (t + 1024 + off < HBINS) ? hist[t + 1024 + off] : 0u;
      u32 a3 = (t + 1536 + off < HBINS) ? hist[t + 1536 + off] : 0u;
      __syncthreads();
      hist[t] += a0; hist[t + 512] += a1; hist[t + 1024] += a2; hist[t + 1536] += a3;
      __syncthreads();
    }
    u32 total = hist[0];
    u32 need = (u32)K_ - Gacc;
    if (lvl == 0 && total < (u32)K_) {
      loKey = 1u;              // undershoot: take all valid (count < 200 <= POOL)
      done = true;
    } else {
      for (int h = t; h < HBINS; h += TPB_N) {
        u32 Sb = hist[h];
        u32 Sn = (h + 1 < HBINS) ? hist[h + 1] : 0u;
        if (Sb >= need && Sn < need) { sh_sel = (u32)h; sh_Sb = Sb; sh_Sn = Sn; }
      }
      __syncthreads();
      prefix = (prefix << ((lvl == 0) ? 11 : 10)) | sh_sel;
      u32 candTotal = Gacc + sh_Sb;   // count(key >= loKey) >= 200 by construction
      Gacc += sh_Sn;                  // count strictly above the boundary bin
      loKey = prefix << shift;
      done = (candTotal <= (u32)POOL) || (lvl == 2);
      __syncthreads();
    }
  }

  // ---- collect pass: all candidates with key >= loKey into pool ----
  if (t == 0) sh_nc = 0u;
  __syncthreads();
  for (int i = t; i < N4_; i += TPB_N) {
    float4 s4 = sc4[i];
    float ss[4] = {s4.x, s4.y, s4.z, s4.w};
#pragma unroll
    for (int c2 = 0; c2 < 4; ++c2) {
      if (ss[c2] > CONF_T) {
        u32 k = __float_as_uint(ss[c2]);
        if (k >= loKey) {
          u32 slot = atomicAdd(&sh_nc, 1u);
          if (slot < (u32)POOL)
            pool[slot] = ((u64)k << 32) | (u64)(0xFFFFFFFFu - (u32)(i * 4 + c2));
        }
      }
    }
  }
  __syncthreads();
  u32 nc = sh_nc < (u32)POOL ? sh_nc : (u32)POOL;
  for (int i = t; i < POOL; i += TPB_N)
    if ((u32)i >= nc) pool[i] = 0ULL;
  __syncthreads();

  // ---- bitonic sort of 1024 composites, descending; 512 threads = 512 pairs ----
  for (int kk = 2; kk <= POOL; kk <<= 1) {
    for (int j = kk >> 1; j > 0; j >>= 1) {
      int pos = ((t & ~(j - 1)) << 1) | (t & (j - 1));
      int par = pos | j;
      u64 a = pool[pos], b2 = pool[par];
      bool desc = ((pos & kk) == 0);
      if (desc ? (a < b2) : (a > b2)) { pool[pos] = b2; pool[par] = a; }
      __syncthreads();
    }
  }
  // pool[0..199] == exact top_k(masked scores) with index-ascending tie order.

  // ---- decode boxes for top-200 ----
  float x1 = 0.f, y1 = 0.f, x2 = 0.f, y2 = 0.f, area = 0.f, scv = 0.f;
  if (t < K_) {
    u64 e = pool[t];
    u32 kb = (u32)(e >> 32);
    if (kb != 0u) {
      scv = __uint_as_float(kb);
      u32 idx = 0xFFFFFFFFu - (u32)(e & 0xFFFFFFFFu);
      int nn = (idx < (u32)N_) ? (int)idx : (int)(idx - N_);
      float4 l = (idx < (u32)N_) ? loc1[(size_t)bimg * N_ + nn]
                                 : loc2[(size_t)bimg * N_ + nn];
      float4 d = dbox[nn];
      float cx = d.x + l.x * 0.1f * d.z;
      float cy = d.y + l.y * 0.1f * d.w;
      float w = d.z * expf(l.z * 0.2f);
      float h = d.w * expf(l.w * 0.2f);
      x1 = cx - w * 0.5f; y1 = cy - h * 0.5f;
      x2 = cx + w * 0.5f; y2 = cy + h * 0.5f;
      if (idx >= (u32)N_) {   // horizontal flip of second (TTA) view
        float tmp = 1.0f - x2; x2 = 1.0f - x1; x1 = tmp;
      }
      area = (x2 - x1) * (y2 - y1);
    }
    bx1[t] = x1; by1[t] = y1; bx2[t] = x2; by2[t] = y2; bar[t] = area;
  }
  {
    bool myvalid = (t < K_) && (scv > CONF_T);
    u64 bal = __ballot(myvalid);
    if ((t & 63) == 0 && (t >> 6) < 4) validmask[t >> 6] = bal;
  }
  __syncthreads();

  // ---- IoU>thresh bitmask rows: thread j owns row j ----
  if (t < K_) {
    u64 r0 = 0, r1 = 0, r2 = 0, r3 = 0;
    for (int k2 = 0; k2 < K_; ++k2) {
      float ox1 = fmaxf(x1, bx1[k2]);
      float oy1 = fmaxf(y1, by1[k2]);
      float ox2 = fminf(x2, bx2[k2]);
      float oy2 = fminf(y2, by2[k2]);
      float iw = fmaxf(ox2 - ox1, 0.0f);
      float ih = fmaxf(oy2 - oy1, 0.0f);
      float inter = iw * ih;
      float uni = area + bar[k2] - inter;
      u64 bit = (inter > NMS_T * uni) ? 1ULL : 0ULL;
      u64 sh2 = bit << (k2 & 63);
      int w2 = k2 >> 6;
      if (w2 == 0) r0 |= sh2; else if (w2 == 1) r1 |= sh2;
      else if (w2 == 2) r2 |= sh2; else r3 |= sh2;
    }
    rowmask[t][0] = r0; rowmask[t][1] = r1; rowmask[t][2] = r2; rowmask[t][3] = r3;
  }
  __syncthreads();

  // ---- sequential greedy scan: wave 0, replicated register state ----
  if (t < 64) {
    u64 v0 = validmask[0], v1 = validmask[1], v2 = validmask[2], v3 = validmask[3];
    u64 s0 = 0, s1 = 0, s2 = 0, s3 = 0;
    u64 k0 = 0, k1 = 0, k2m = 0, k3 = 0;
#pragma unroll 4
    for (int j = 0; j < K_; ++j) {
      u64 r0 = rowmask[j][0], r1 = rowmask[j][1], r2 = rowmask[j][2], r3 = rowmask[j][3];
      int q = j >> 6;
      u64 bit = 1ULL << (j & 63);
      u64 vw = (q == 0) ? v0 : (q == 1) ? v1 : (q == 2) ? v2 : v3;
      u64 sw = (q == 0) ? s0 : (q == 1) ? s1 : (q == 2) ? s2 : s3;
      if ((vw & bit) && !(sw & bit)) {
        s0 |= r0; s1 |= r1; s2 |= r2; s3 |= r3;
        if (q == 0) k0 |= bit; else if (q == 1) k1 |= bit;
        else if (q == 2) k2m |= bit; else k3 |= bit;
      }
    }
    if (t == 0) { keepmask[0] = k0; keepmask[1] = k1; keepmask[2] = k2m; keepmask[3] = k3; }
  }
  __syncthreads();

  // ---- compact kept entries ----
  if (t < K_) {
    int q = t >> 6, bitp = t & 63;
    u64 kw = keepmask[q];
    if ((kw >> bitp) & 1ULL) {
      int pos = (int)__popcll(kw & ((1ULL << bitp) - 1ULL));
      for (int w2 = 0; w2 < q; ++w2) pos += (int)__popcll(keepmask[w2]);
      float* o = out + ((((size_t)bimg * C_) + cls) * K_ + (size_t)pos) * 5;
      o[0] = scv; o[1] = x1; o[2] = y1; o[3] = x2; o[4] = y2;
    }
  }
}

extern "C" void kernel_launch(void* const* d_in, const int* in_sizes, int n_in,
                              void* d_out, int out_size, void* d_ws, size_t ws_size,
                              hipStream_t stream) {
  const float* loc1 = (const float*)d_in[0];
  const float* conf1 = (const float*)d_in[1];
  const float* loc2 = (const float*)d_in[2];
  const float* conf2 = (const float*)d_in[3];
  const float* dbox = (const float*)d_in[4];
  float* out = (float*)d_out;
  float* scores = (float*)d_ws;   // [B, NCLS, 2N] fp32 = 44.7 MB

  hipMemsetAsync(d_out, 0, (size_t)out_size * sizeof(float), stream);

  dim3 g1((N_ + TPB_S - 1) / TPB_S, B_, 2);
  softmax_kernel<<<g1, TPB_S, 0, stream>>>(conf1, conf2, scores);

  nms_kernel<<<B_ * NCLS, TPB_N, 0, stream>>>(
      scores, (const float4*)loc1, (const float4*)loc2, (const float4*)dbox, out);
}

// Round 4
// 185.895 us; speedup vs baseline: 1.6135x; 1.0722x over previous
//
#include <hip/hip_runtime.h>

#define B_ 32
#define N_ 8732
#define N2_ 17464
#define N4_ 4366      // N2_/4 exactly
#define C_ 21
#define NCLS 20
#define K_ 200
#define CONF_T 0.01f
#define NMS_T 0.45f
#define TPB_S 256
#define TPB_N 512
#define POOL 1024
#define HBINS 2048

typedef unsigned long long u64;
typedef unsigned int u32;

// ---------------------------------------------------------------------------
// Kernel 1: softmax over C=21. LDS-staged float4 loads, __expf + single
// reciprocal, in-place LDS transpose, float4 coalesced writeout to
// [B, NCLS, 2N] (class 0 dropped). Grid: (ceil(N/256), B, 2 views).
// ---------------------------------------------------------------------------
__global__ __launch_bounds__(TPB_S) void softmax_kernel(
    const float* __restrict__ conf1, const float* __restrict__ conf2,
    float* __restrict__ scores)
{
  __shared__ float lds[TPB_S * C_];   // 21 KB
  const int t = threadIdx.x;
  const int tile = blockIdx.x * TPB_S;
  const int b = blockIdx.y;
  const int view = blockIdx.z;
  int cnt = N_ - tile; if (cnt > TPB_S) cnt = TPB_S;   // 256 or 28 (both %4==0)
  const float* conf = view ? conf2 : conf1;
  const float4* src = (const float4*)(conf + ((size_t)b * N_ + tile) * C_);  // 16B-aligned
  float4* l4 = (float4*)lds;
  const int n4 = (cnt * C_) >> 2;
  for (int i = t; i < n4; i += TPB_S) l4[i] = src[i];
  __syncthreads();
  if (t < cnt) {
    float x[C_];
#pragma unroll
    for (int i = 0; i < C_; ++i) x[i] = lds[t * C_ + i];  // stride-21: 2-way, free
    float m = x[0];
#pragma unroll
    for (int i = 1; i < C_; ++i) m = fmaxf(m, x[i]);
    float e[C_];
    float sum = 0.0f;
#pragma unroll
    for (int i = 0; i < C_; ++i) { e[i] = __expf(x[i] - m); sum += e[i]; }
    float inv = 1.0f / sum;   // one IEEE div, not 20
    // in-place transpose: class c (1..20) -> slot t*21 + (c-1)
#pragma unroll
    for (int c = 1; c < C_; ++c) lds[t * C_ + (c - 1)] = e[c] * inv;
  }
  __syncthreads();
  // cooperative float4 writeout, one contiguous run per class plane
  const int nf4 = cnt >> 2;            // 64 or 7
  const int tot = NCLS * nf4;          // 1280 or 140
  float* base = scores + ((size_t)b * NCLS) * N2_ + (size_t)view * N_ + tile;
  for (int f = t; f < tot; f += TPB_S) {
    int c, a0;
    if (nf4 == 64) { c = f >> 6; a0 = (f & 63) << 2; }
    else           { c = f / 7;  a0 = (f - c * 7) << 2; }
    float4 o;
    o.x = lds[(a0 + 0) * C_ + c];
    o.y = lds[(a0 + 1) * C_ + c];
    o.z = lds[(a0 + 2) * C_ + c];
    o.w = lds[(a0 + 3) * C_ + c];
    *(float4*)(base + (size_t)c * N2_ + a0) = o;   // 16B/lane coalesced
  }
}

// ---------------------------------------------------------------------------
// Kernel 2: per-(image,class). Scores register-cached (ONE global pass):
// 2048-bin radix cutoff (shuffle-scan) -> ballot-collect <=1024 candidates ->
// rank-by-counting (no sort) -> decode -> split IoU bitmask -> serial scan ->
// compact. One 512-thread block per (b, c).
// ---------------------------------------------------------------------------
__global__ __launch_bounds__(TPB_N) void nms_kernel(
    const float* __restrict__ scores,
    const float4* __restrict__ loc1,
    const float4* __restrict__ loc2,
    const float4* __restrict__ dbox,
    float* __restrict__ out)
{
  const int t = threadIdx.x;
  const int lane = t & 63;
  const int wv = t >> 6;
  const int bimg = blockIdx.x / NCLS;
  const int cls = 1 + (blockIdx.x % NCLS);
  const float4* sc4 = (const float4*)(scores + ((size_t)bimg * NCLS + (cls - 1)) * N2_);

  __shared__ u32 hist[HBINS];            // 8 KB
  __shared__ u64 pool[POOL];             // 8 KB
  __shared__ u64 spool[256];             // 2 KB, rank-ordered top-200
  __shared__ float4 bb[K_];              // 3.2 KB
  __shared__ float bar[K_];
  __shared__ u64 rowmask[K_][4];         // 6.4 KB
  __shared__ u64 validmask[4];
  __shared__ u64 keepmask[4];
  __shared__ u32 wtot[8];
  __shared__ u32 sh_sel, sh_Sb, sh_Sn, sh_nc;

  // ---- load this (b,c)'s 17464 scores into registers: the ONLY global pass ----
  float4 v[9];
#pragma unroll
  for (int k = 0; k < 9; ++k) {
    int i = t + k * TPB_N;
    v[k] = (i < N4_) ? sc4[i] : make_float4(0.f, 0.f, 0.f, 0.f);
  }

  // ---- multi-level radix cutoff: need <= count(key>=loKey) <= POOL ----
  u32 prefix = 0, Gacc = 0, loKey = 0;
  bool done = false;
  for (int lvl = 0; lvl < 3 && !done; ++lvl) {
    const int shift = (lvl == 0) ? 20 : (lvl == 1) ? 10 : 0;
    const u32 bmask = (lvl == 0) ? 2047u : 1023u;
    const int mshift = shift + 10;   // prefix-match shift (lvl>0)
    for (int h = t; h < HBINS; h += TPB_N) hist[h] = 0u;
    __syncthreads();
#pragma unroll
    for (int k = 0; k < 9; ++k) {
      float ss[4] = {v[k].x, v[k].y, v[k].z, v[k].w};
#pragma unroll
      for (int c2 = 0; c2 < 4; ++c2) {
        float s = ss[c2];
        if (s > CONF_T) {
          u32 key = __float_as_uint(s);   // positive fp32: bits order-isomorphic
          if (lvl == 0 || (key >> mshift) == prefix)
            atomicAdd(&hist[(key >> shift) & bmask], 1u);
        }
      }
    }
    __syncthreads();
    // ---- suffix sums S[h] = sum_{h'>=h} hist[h']: 4 bins/thread + wave scan ----
    u32 c0 = hist[4 * t + 0], c1 = hist[4 * t + 1], c2b = hist[4 * t + 2], c3 = hist[4 * t + 3];
    u32 T = c0 + c1 + c2b + c3;
    u32 x = T;
#pragma unroll
    for (int off = 1; off < 64; off <<= 1) {
      u32 y = __shfl_down(x, off);
      if (lane + off < 64) x += y;
    }                                   // x = suffix-incl sum of thread totals in wave
    if (lane == 0) wtot[wv] = x;
    __syncthreads();
    u32 wafter = 0;
    for (int w = wv + 1; w < 8; ++w) wafter += wtot[w];
    u32 after_me = (x - T) + wafter;    // totals of threads strictly after t
    u32 S3 = c3 + after_me, S2 = c2b + S3, S1 = c1 + S2, S0 = c0 + S1;
    hist[4 * t + 0] = S0; hist[4 * t + 1] = S1; hist[4 * t + 2] = S2; hist[4 * t + 3] = S3;
    __syncthreads();
    u32 total = hist[0];
    u32 need = (u32)K_ - Gacc;
    if (lvl == 0 && total < (u32)K_) {
      loKey = 1u;                       // undershoot: take all valid (<200)
      done = true;
    } else {
      for (int h = t; h < HBINS; h += TPB_N) {
        u32 Sb = hist[h];
        u32 Sn = (h + 1 < HBINS) ? hist[h + 1] : 0u;
        if (Sb >= need && Sn < need) { sh_sel = (u32)h; sh_Sb = Sb; sh_Sn = Sn; }
      }
      __syncthreads();
      prefix = (prefix << ((lvl == 0) ? 11 : 10)) | sh_sel;
      u32 candTotal = Gacc + sh_Sb;
      Gacc += sh_Sn;
      loKey = prefix << shift;
      done = (candTotal <= (u32)POOL) || (lvl == 2);
      __syncthreads();
    }
  }

  // ---- ballot-collect candidates (key >= loKey) into pool, 1 atomic/wave ----
  if (t == 0) sh_nc = 0u;
  __syncthreads();
#pragma unroll
  for (int k = 0; k < 9; ++k) {
    int i = t + k * TPB_N;
    float ss[4] = {v[k].x, v[k].y, v[k].z, v[k].w};
#pragma unroll
    for (int c2 = 0; c2 < 4; ++c2) {
      float s = ss[c2];
      u32 key = __float_as_uint(s);
      bool pred = (s > CONF_T) && (key >= loKey);
      u64 bal = __ballot(pred);
      if (bal) {
        u32 wb = 0;
        if (lane == 0) wb = atomicAdd(&sh_nc, (u32)__popcll(bal));
        wb = __shfl(wb, 0);
        if (pred) {
          u32 pos = wb + (u32)__popcll(bal & ((1ULL << lane) - 1ULL));
          if (pos < (u32)POOL)
            pool[pos] = ((u64)key << 32) | (u64)(0xFFFFFFFFu - (u32)(i * 4 + c2));
        }
      }
    }
  }
  __syncthreads();

  // ---- rank-by-counting: composite keys unique -> rank = #{keys > mine} ----
  u32 nc = sh_nc < (u32)POOL ? sh_nc : (u32)POOL;
  if (t < 256) spool[t] = 0ULL;
  u64 my0 = (t < (int)nc) ? pool[t] : 0ULL;
  u64 my1 = (t + TPB_N < (int)nc) ? pool[t + TPB_N] : 0ULL;
  __syncthreads();
  u32 r0 = 0, r1 = 0;
#pragma unroll 4
  for (u32 k = 0; k < nc; ++k) {        // broadcast LDS reads, barrier-free
    u64 pk = pool[k];
    r0 += (pk > my0) ? 1u : 0u;
    r1 += (pk > my1) ? 1u : 0u;
  }
  if (my0 != 0ULL && r0 < (u32)K_) spool[r0] = my0;
  if (my1 != 0ULL && r1 < (u32)K_) spool[r1] = my1;
  __syncthreads();
  // spool[0..199] == exact top_k (desc score, ties by ascending index)

  // ---- decode boxes for top-200 ----
  float x1 = 0.f, y1 = 0.f, x2 = 0.f, y2 = 0.f, area = 0.f, scv = 0.f;
  if (t < K_) {
    u64 e = spool[t];
    u32 kb = (u32)(e >> 32);
    if (kb != 0u) {
      scv = __uint_as_float(kb);
      u32 idx = 0xFFFFFFFFu - (u32)(e & 0xFFFFFFFFu);
      int nn = (idx < (u32)N_) ? (int)idx : (int)(idx - N_);
      float4 l = (idx < (u32)N_) ? loc1[(size_t)bimg * N_ + nn]
                                 : loc2[(size_t)bimg * N_ + nn];
      float4 d = dbox[nn];
      float cx = d.x + l.x * 0.1f * d.z;
      float cy = d.y + l.y * 0.1f * d.w;
      float w = d.z * __expf(l.z * 0.2f);
      float h = d.w * __expf(l.w * 0.2f);
      x1 = cx - w * 0.5f; y1 = cy - h * 0.5f;
      x2 = cx + w * 0.5f; y2 = cy + h * 0.5f;
      if (idx >= (u32)N_) {   // horizontal flip of second (TTA) view
        float tmp = 1.0f - x2; x2 = 1.0f - x1; x1 = tmp;
      }
      area = (x2 - x1) * (y2 - y1);
    }
    bb[t] = make_float4(x1, y1, x2, y2);
    bar[t] = area;
  }
  {
    bool myvalid = (t < K_) && (scv > CONF_T);
    u64 bal = __ballot(myvalid);
    if (lane == 0 && wv < 4) validmask[wv] = bal;
  }
  __syncthreads();

  // ---- IoU>thresh bitmask rows, split across two thread groups ----
  // group A (t<200): row t, columns 0..127 -> words 0,1
  // group B (256<=t<456): row t-256, columns 128..199 -> words 2,3
  {
    int row = -1, cb = 0;
    if (t < K_) { row = t; cb = 0; }
    else if (t >= 256 && t < 256 + K_) { row = t - 256; cb = 128; }
    if (row >= 0) {
      float4 mb = bb[row];
      float ma = bar[row];
      u64 mlo = 0, mhi = 0;   // word pair: (cb>>6)+0, (cb>>6)+1
      int ce = cb ? K_ : 128;
      for (int k2 = cb; k2 < ce; ++k2) {
        float4 ob = bb[k2];
        float ox1 = fmaxf(mb.x, ob.x);
        float oy1 = fmaxf(mb.y, ob.y);
        float ox2 = fminf(mb.z, ob.z);
        float oy2 = fminf(mb.w, ob.w);
        float inter = fmaxf(ox2 - ox1, 0.f) * fmaxf(oy2 - oy1, 0.f);
        float uni = ma + bar[k2] - inter;
        u64 bit = (inter > NMS_T * uni) ? 1ULL : 0ULL;
        u64 sh2 = bit << (k2 & 63);
        if (k2 & 64) mhi |= sh2; else mlo |= sh2;  // bit6 selects word within pair
      }
      rowmask[row][(cb >> 6) + 0] = mlo;
      rowmask[row][(cb >> 6) + 1] = mhi;
    }
  }
  __syncthreads();

  // ---- sequential greedy scan: wave 0, replicated register state ----
  if (t < 64) {
    u64 v0 = validmask[0], v1 = validmask[1], v2 = validmask[2], v3 = validmask[3];
    u64 s0 = 0, s1 = 0, s2 = 0, s3 = 0;
    u64 k0 = 0, k1 = 0, k2m = 0, k3 = 0;
#pragma unroll 8
    for (int j = 0; j < K_; ++j) {
      u64 q0 = rowmask[j][0], q1 = rowmask[j][1], q2 = rowmask[j][2], q3 = rowmask[j][3];
      int q = j >> 6;
      u64 bit = 1ULL << (j & 63);
      u64 vw = (q == 0) ? v0 : (q == 1) ? v1 : (q == 2) ? v2 : v3;
      u64 sw = (q == 0) ? s0 : (q == 1) ? s1 : (q == 2) ? s2 : s3;
      if ((vw & bit) && !(sw & bit)) {
        s0 |= q0; s1 |= q1; s2 |= q2; s3 |= q3;
        if (q == 0) k0 |= bit; else if (q == 1) k1 |= bit;
        else if (q == 2) k2m |= bit; else k3 |= bit;
      }
    }
    if (t == 0) { keepmask[0] = k0; keepmask[1] = k1; keepmask[2] = k2m; keepmask[3] = k3; }
  }
  __syncthreads();

  // ---- compact kept entries ----
  if (t < K_) {
    int q = t >> 6, bitp = t & 63;
    u64 kw = keepmask[q];
    if ((kw >> bitp) & 1ULL) {
      int pos = (int)__popcll(kw & ((1ULL << bitp) - 1ULL));
      for (int w2 = 0; w2 < q; ++w2) pos += (int)__popcll(keepmask[w2]);
      float* o = out + ((((size_t)bimg * C_) + cls) * K_ + (size_t)pos) * 5;
      o[0] = scv; o[1] = x1; o[2] = y1; o[3] = x2; o[4] = y2;
    }
  }
}

extern "C" void kernel_launch(void* const* d_in, const int* in_sizes, int n_in,
                              void* d_out, int out_size, void* d_ws, size_t ws_size,
                              hipStream_t stream) {
  const float* loc1 = (const float*)d_in[0];
  const float* conf1 = (const float*)d_in[1];
  const float* loc2 = (const float*)d_in[2];
  const float* conf2 = (const float*)d_in[3];
  const float* dbox = (const float*)d_in[4];
  float* out = (float*)d_out;
  float* scores = (float*)d_ws;   // [B, NCLS, 2N] fp32 = 44.7 MB

  hipMemsetAsync(d_out, 0, (size_t)out_size * sizeof(float), stream);

  dim3 g1((N_ + TPB_S - 1) / TPB_S, B_, 2);
  softmax_kernel<<<g1, TPB_S, 0, stream>>>(conf1, conf2, scores);

  nms_kernel<<<B_ * NCLS, TPB_N, 0, stream>>>(
      scores, (const float4*)loc1, (const float4*)loc2, (const float4*)dbox, out);
}